// Round 7
// baseline (270.268 us; speedup 1.0000x reference)
//
#include <hip/hip_runtime.h>
#include <hip/hip_bf16.h>
#include <math.h>

#define N_ENT   50000
#define N_REL   237
#define N_TYPE  4000
#define DE      100
#define NOUT    128
#define DT      200
#define N_EDGE  800000
#define B_SZ    4096
#define ALPHA   0.2f
#define EPS     1e-5f
#define NUM_FILT 32
#define CONV_W_OUT 60
#define POOL_W  30
#define FC_LEN  960
#define KP      224
#define NTP     4032   // logits N padded to 63*64
#define EBCAP   96     // max edges per slot (Poisson(16), max deg ~45 in 4k slots)

typedef unsigned short ushort_t;
typedef __attribute__((ext_vector_type(8))) short bf16x8;
typedef __attribute__((ext_vector_type(4))) float f32x4;

// ---------------- diagnostic fill (f32) ----------------
__global__ void k_fillconst(float* p, long n, float val) {
    long i = (long)blockIdx.x * blockDim.x + threadIdx.x;
    long stride = (long)gridDim.x * blockDim.x;
    for (; i < n; i += stride) p[i] = val;
}

// ------- merged: zero-fill (blocks 0..57) || wa1/wa2/rw precompute (block 58) -------
// zero region: flags[50000] + (dead slotent) + ecount[4096] + sums[448] = 234,560 B
#define ZERO_F4 14660
__global__ void k_fillprep(float4* zp, const float* Wf, const float* a_vec,
                           const float* Rw, float* wa1, float* wa2, float* rw) {
    if (blockIdx.x < 58) {
        int i = blockIdx.x * 256 + threadIdx.x;
        if (i < ZERO_F4) zp[i] = make_float4(0.f, 0.f, 0.f, 0.f);
        return;
    }
    __shared__ float sa[2 * NOUT];
    __shared__ float swa2[DE];
    int t = threadIdx.x;
    sa[t] = a_vec[t];
    __syncthreads();
    if (t < DE) {
        float s1 = 0.f, s2 = 0.f;
        for (int j = 0; j < NOUT; j++) {
            float w = Wf[t * NOUT + j];
            s1 += w * sa[j];
            s2 += w * sa[NOUT + j];
        }
        wa1[t] = s1; wa2[t] = s2; swa2[t] = s2;
    }
    __syncthreads();
    if (t < N_REL) {
        float s = 0.f;
        for (int k = 0; k < DE; k++) s += Rw[t * DE + k] * swa2[k];
        rw[t] = s;
    }
}

// ------- merged: direct-slot flags (blocks 0..15) || per-entity dots (16..) -------
// flags[xb[i]] = i+1 : plain store, benign race — any winning batch index is a
// valid bucket id; duplicates carry identical aggregation so output is invariant.
__global__ void k_flagsent(const int* xb, int* flags,
                           const float* Ew, const float* wa1, const float* wa2,
                           float* ha, float* ew) {
    if (blockIdx.x < 16) {
        int i = blockIdx.x * 256 + threadIdx.x;
        if (i < B_SZ) flags[xb[i]] = i + 1;
        return;
    }
    int wid = (blockIdx.x - 16) * 4 + (threadIdx.x >> 6);
    int lane = threadIdx.x & 63;
    if (wid >= N_ENT) return;
    float s1 = 0.f, s2 = 0.f;
    if (lane < DE / 2) {
        const float2* p = (const float2*)(Ew + (size_t)wid * DE);
        float2 v = p[lane];
        s1 = v.x * wa1[2 * lane] + v.y * wa1[2 * lane + 1];
        s2 = v.x * wa2[2 * lane] + v.y * wa2[2 * lane + 1];
    }
    for (int off = 32; off > 0; off >>= 1) {
        s1 += __shfl_down(s1, off);
        s2 += __shfl_down(s2, off);
    }
    if (lane == 0) { ha[wid] = s1; ew[wid] = s2; }
}

// ------- single-pass scatter into fixed-capacity buckets -------
__global__ void k_scatter96(const int* ei, const int* et, const int* flags,
                            int* ecount, int2* ebuck) {
    int e = blockIdx.x * blockDim.x + threadIdx.x;
    if (e >= N_EDGE) return;
    int s = flags[ei[N_EDGE + e]];
    if (!s) return;
    int idx = atomicAdd(&ecount[s - 1], 1);
    if (idx < EBCAP)
        ebuck[(size_t)(s - 1) * EBCAP + idx] = make_int2(ei[e], et[e]);
}

// ------- per-slot aggregation: 4 quarters process alternate edges (quartered chain) -------
// slot = batch index; entity = xb[slot]. No-edge slots write zeros; never read.
__global__ void k_agg(const int* xb, const int* ecount,
                      const int2* ebuck, const float* Ew, const float* Rw,
                      const float* ha, const float* ew, const float* rw,
                      float* aggc) {
    __shared__ float sacc[3][DE];
    __shared__ float sden[3];
    int slot = blockIdx.x;
    int t = threadIdx.x;          // 512
    int q = t >> 7;               // 0..3
    int tl = t & 127;
    int n = min(ecount[slot], EBCAP);
    const int2* eb = ebuck + (size_t)slot * EBCAP;
    float hae = ha[xb[slot]];
    float acc = 0.f, den = 0.f;
    for (int j = q; j < n; j += 4) {
        int2 p = eb[j];
        float sc = hae + ew[p.x] - rw[p.y];
        sc = sc >= 0.f ? sc : ALPHA * sc;
        float ex = expf(sc);
        den += ex;
        if (tl < DE) acc += ex * (Ew[(size_t)p.x * DE + tl] - Rw[(size_t)p.y * DE + tl]);
    }
    if (q > 0) {
        if (tl < DE) sacc[q - 1][tl] = acc;
        if (tl == 0) sden[q - 1] = den;
    }
    __syncthreads();
    if (q == 0 && tl < DE) {
        float a = acc + sacc[0][tl] + sacc[1][tl] + sacc[2][tl];
        float d = den + sden[0] + sden[1] + sden[2];
        aggc[(size_t)slot * DE + tl] = a / (d + 1e-16f);
    }
}

// -------- gather + project + elu + conv-u partial stats (no atomics) --------
__global__ void k_gatherconv(const int* xb, const int* flags, const float* aggc,
                             const float* Wf, const float* convw,
                             float* ebuf, float* gps, float* gpq, float* cpart) {
    __shared__ float row[DE];
    __shared__ float xs[NOUT];
    __shared__ float cw[NUM_FILT * 9];
    __shared__ float red[NOUT], red2[NOUT];
    int b = blockIdx.x, t = threadIdx.x;
    int slot = flags[xb[b]] - 1;
    if (t < DE) row[t] = aggc[(size_t)slot * DE + t];
    for (int i = t; i < NUM_FILT * 9; i += 128) cw[i] = convw[i];
    __syncthreads();
    float acc = 0.f;
    for (int k = 0; k < DE; k++) acc += row[k] * Wf[k * NOUT + t];
    float x = acc > 0.f ? acc : expm1f(acc);
    xs[t] = x;
    ebuf[(size_t)b * NOUT + t] = x;
    red[t] = x; red2[t] = x * x;
    __syncthreads();
    for (int s = 64; s > 0; s >>= 1) {
        if (t < s) { red[t] += red[t + s]; red2[t] += red2[t + s]; }
        __syncthreads();
    }
    if (t == 0) { gps[b] = red[0]; gpq[b] = red2[0]; }
    int c = t >> 2, wg = t & 3;
    float ls = 0.f, lq = 0.f;
    for (int i = 0; i < 15; i++) {
        int w = wg + 4 * i;
        float u = 0.f;
        #pragma unroll
        for (int j = 0; j < 9; j++) u += cw[c * 9 + j] * xs[2 * w + j];
        ls += u; lq += u * u;
    }
    __syncthreads();
    red[t] = ls; red2[t] = lq;
    __syncthreads();
    if (wg == 0) {
        float s = red[t] + red[t + 1] + red[t + 2] + red[t + 3];
        float q = red2[t] + red2[t + 1] + red2[t + 2] + red2[t + 3];
        cpart[b * 64 + c] = s;
        cpart[b * 64 + 32 + c] = q;
    }
}

// ------- reduce stats per filter -> A_c, B_c -------
__global__ void k_redAB(const float* gps, const float* gpq, const float* cpart,
                        const float* g1, const float* g3, const float* b3, float* AB) {
    __shared__ float r1[256], r2[256], r3[256], r4[256];
    int c = blockIdx.x, t = threadIdx.x;
    float s = 0.f, q = 0.f, cs = 0.f, cq = 0.f;
    for (int b = t; b < B_SZ; b += 256) {
        s += gps[b]; q += gpq[b];
        cs += cpart[b * 64 + c]; cq += cpart[b * 64 + 32 + c];
    }
    r1[t] = s; r2[t] = q; r3[t] = cs; r4[t] = cq;
    __syncthreads();
    for (int k = 128; k > 0; k >>= 1) {
        if (t < k) { r1[t] += r1[t+k]; r2[t] += r2[t+k]; r3[t] += r3[t+k]; r4[t] += r4[t+k]; }
        __syncthreads();
    }
    if (t == 0) {
        float N1 = (float)(B_SZ * NOUT);
        float m1 = r1[0] / N1;
        float v1 = r2[0] / N1 - m1 * m1;
        float s1 = g1[0] * rsqrtf(v1 + EPS);
        float Nc = (float)(B_SZ * CONV_W_OUT);
        float mu = r3[0] / Nc;
        float vu = r4[0] / Nc - mu * mu;
        float A = g3[c] * s1 * rsqrtf(s1 * s1 * vu + EPS);
        AB[c] = A;
        AB[32 + c] = b3[c] - A * mu;
    }
}

// ------- merged: conv+pool (blocks 0..4095) || fc_w/T_w repacks (4096..) -------
__global__ void k_poolpads(const float* ebuf, const float* convw, const float* AB,
                           __hip_bfloat16* pooled, const float* fcw, const float* tw,
                           __hip_bfloat16* bfc, __hip_bfloat16* b2) {
    int t = threadIdx.x;   // 128
    if (blockIdx.x >= B_SZ) {
        int i = (blockIdx.x - B_SZ) * 128 + t;
        if (i < KP * FC_LEN) {
            bfc[i] = __float2bfloat16((i < DT * FC_LEN) ? fcw[i] : 0.f);
        } else {
            int j = i - KP * FC_LEN;
            if (j < NTP * KP) {
                int n = j / KP, k = j - n * KP;
                float v = (n < N_TYPE && k < DT) ? tw[n * DT + k] : 0.f;
                b2[j] = __float2bfloat16(v);
            }
        }
        return;
    }
    __shared__ float xs[NOUT];
    __shared__ float cw[NUM_FILT * 9];
    __shared__ float sA[32], sB[32];
    int b = blockIdx.x;
    xs[t] = ebuf[(size_t)b * NOUT + t];
    for (int i = t; i < NUM_FILT * 9; i += 128) cw[i] = convw[i];
    if (t < 32) { sA[t] = AB[t]; sB[t] = AB[32 + t]; }
    __syncthreads();
    int c = t >> 2, wg = t & 3;
    float A = sA[c], Bv = sB[c];
    for (int i = 0; i < 8; i++) {
        int w2 = wg + 4 * i;
        if (w2 < POOL_W) {
            int w = 2 * w2;
            float u0 = 0.f, u1 = 0.f;
            #pragma unroll
            for (int j = 0; j < 9; j++) {
                float cv = cw[c * 9 + j];
                u0 += cv * xs[2 * w + j];
                u1 += cv * xs[2 * w + 2 + j];
            }
            float z0 = fmaxf(A * u0 + Bv, 0.f);
            float z1 = fmaxf(A * u1 + Bv, 0.f);
            pooled[((size_t)b * NUM_FILT + c) * POOL_W + w2] = __float2bfloat16(fmaxf(z0, z1));
        }
    }
}

// ---------------- MFMA GEMM with swapped-operand transposed epilogue ----------------
// mfma(b, a, acc): lane&15 = output ROW, (lane>>4)*4+reg = 4 contiguous output COLS
// MODE 0: C = A@B^T + bias (f32) + fused bn2 stats atomics into sums[448].
// MODE 1: sigmoid(A@B^T + bias), guard cc < nbias.
template<int MODE, int K, int NB>
__launch_bounds__(256, 4)
__global__ void k_gemm(const ushort_t* A, const ushort_t* Bm, const float* bias,
                       int ldc, int nbias, float* Cf, float* sums) {
    int wave = threadIdx.x >> 6, lane = threadIdx.x & 63;
    int m0 = blockIdx.x * 128 + wave * 32;
    int n0 = blockIdx.y * (16 * NB);
    int rsel = lane & 15, ksel = (lane >> 4) * 8;
    const ushort_t* pa0 = A + (size_t)(m0 + rsel) * K + ksel;
    const ushort_t* pa1 = pa0 + (size_t)16 * K;
    const ushort_t* pb[NB];
    #pragma unroll
    for (int j = 0; j < NB; j++) pb[j] = Bm + (size_t)(n0 + j * 16 + rsel) * K + ksel;
    f32x4 acc0[NB], acc1[NB];
    #pragma unroll
    for (int j = 0; j < NB; j++) { acc0[j] = (f32x4){0.f,0.f,0.f,0.f}; acc1[j] = acc0[j]; }
    if constexpr (K <= 256) {
        #pragma unroll
        for (int k = 0; k < K; k += 32) {
            bf16x8 a0 = *(const bf16x8*)(pa0 + k);
            bf16x8 a1 = *(const bf16x8*)(pa1 + k);
            #pragma unroll
            for (int j = 0; j < NB; j++) {
                bf16x8 b = *(const bf16x8*)(pb[j] + k);
                acc0[j] = __builtin_amdgcn_mfma_f32_16x16x32_bf16(b, a0, acc0[j], 0, 0, 0);
                acc1[j] = __builtin_amdgcn_mfma_f32_16x16x32_bf16(b, a1, acc1[j], 0, 0, 0);
            }
        }
    } else {
        #pragma unroll 4
        for (int k = 0; k < K; k += 32) {
            bf16x8 a0 = *(const bf16x8*)(pa0 + k);
            bf16x8 a1 = *(const bf16x8*)(pa1 + k);
            #pragma unroll
            for (int j = 0; j < NB; j++) {
                bf16x8 b = *(const bf16x8*)(pb[j] + k);
                acc0[j] = __builtin_amdgcn_mfma_f32_16x16x32_bf16(b, a0, acc0[j], 0, 0, 0);
                acc1[j] = __builtin_amdgcn_mfma_f32_16x16x32_bf16(b, a1, acc1[j], 0, 0, 0);
            }
        }
    }
    int mloc = lane & 15;
    int nq = (lane >> 4) * 4;
    #pragma unroll
    for (int j = 0; j < NB; j++) {
        int cc = n0 + j * 16 + nq;
        if (cc < nbias) {
            float4 bb = *(const float4*)(bias + cc);
            f32x4 v0 = acc0[j], v1 = acc1[j];
            float4 r0, r1;
            if (MODE == 0) {
                r0 = make_float4(v0[0] + bb.x, v0[1] + bb.y, v0[2] + bb.z, v0[3] + bb.w);
                r1 = make_float4(v1[0] + bb.x, v1[1] + bb.y, v1[2] + bb.z, v1[3] + bb.w);
            } else {
                r0.x = __builtin_amdgcn_rcpf(1.f + __expf(-(v0[0] + bb.x)));
                r0.y = __builtin_amdgcn_rcpf(1.f + __expf(-(v0[1] + bb.y)));
                r0.z = __builtin_amdgcn_rcpf(1.f + __expf(-(v0[2] + bb.z)));
                r0.w = __builtin_amdgcn_rcpf(1.f + __expf(-(v0[3] + bb.w)));
                r1.x = __builtin_amdgcn_rcpf(1.f + __expf(-(v1[0] + bb.x)));
                r1.y = __builtin_amdgcn_rcpf(1.f + __expf(-(v1[1] + bb.y)));
                r1.z = __builtin_amdgcn_rcpf(1.f + __expf(-(v1[2] + bb.z)));
                r1.w = __builtin_amdgcn_rcpf(1.f + __expf(-(v1[3] + bb.w)));
            }
            *(float4*)(Cf + (size_t)(m0 + mloc) * ldc + cc) = r0;
            *(float4*)(Cf + (size_t)(m0 + 16 + mloc) * ldc + cc) = r1;
            if constexpr (MODE == 0) {
                // fused bn2 partial stats: reduce the 32 rows of this wave's tile
                float s0 = r0.x + r1.x, s1 = r0.y + r1.y, s2 = r0.z + r1.z, s3 = r0.w + r1.w;
                float q0 = r0.x*r0.x + r1.x*r1.x, q1 = r0.y*r0.y + r1.y*r1.y;
                float q2 = r0.z*r0.z + r1.z*r1.z, q3 = r0.w*r0.w + r1.w*r1.w;
                #pragma unroll
                for (int off = 1; off <= 8; off <<= 1) {
                    s0 += __shfl_xor(s0, off); s1 += __shfl_xor(s1, off);
                    s2 += __shfl_xor(s2, off); s3 += __shfl_xor(s3, off);
                    q0 += __shfl_xor(q0, off); q1 += __shfl_xor(q1, off);
                    q2 += __shfl_xor(q2, off); q3 += __shfl_xor(q3, off);
                }
                if (mloc == 0) {
                    atomicAdd(&sums[cc + 0], s0); atomicAdd(&sums[cc + 1], s1);
                    atomicAdd(&sums[cc + 2], s2); atomicAdd(&sums[cc + 3], s3);
                    atomicAdd(&sums[KP + cc + 0], q0); atomicAdd(&sums[KP + cc + 1], q1);
                    atomicAdd(&sums[KP + cc + 2], q2); atomicAdd(&sums[KP + cc + 3], q3);
                }
            }
        }
    }
}

// ------- bn2 apply + relu -> bf16 A2 [B,224]; scale/shift derived inline -------
__global__ void k_bn2apply(const float* fcout, const float* sums,
                           const float* g, const float* bb, __hip_bfloat16* a2) {
    int i = blockIdx.x * blockDim.x + threadIdx.x;
    if (i >= B_SZ * KP) return;
    int t = i % KP;
    float v = 0.f;
    if (t < DT) {
        float mean = sums[t] * (1.f / B_SZ);
        float var = sums[KP + t] * (1.f / B_SZ) - mean * mean;
        float sc = g[t] * rsqrtf(var + EPS);
        float sh = bb[t] - mean * sc;
        v = fcout[i] * sc + sh;
        v = fmaxf(v, 0.f);
    }
    a2[i] = __float2bfloat16(v);
}

extern "C" void kernel_launch(void* const* d_in, const int* in_sizes, int n_in,
                              void* d_out, int out_size, void* d_ws, size_t ws_size,
                              hipStream_t stream) {
    (void)in_sizes; (void)n_in;
    const int*   x_batch = (const int*)d_in[0];
    const int*   ei      = (const int*)d_in[1];
    const int*   etype   = (const int*)d_in[2];
    const float* E_w     = (const float*)d_in[3];
    const float* R_w     = (const float*)d_in[4];
    const float* T_w     = (const float*)d_in[5];
    const float* W_f     = (const float*)d_in[6];
    const float* a_vec   = (const float*)d_in[7];
    const float* conv_w  = (const float*)d_in[8];
    const float* bn1_g   = (const float*)d_in[10];
    const float* bn3_g   = (const float*)d_in[12];
    const float* bn3_b   = (const float*)d_in[13];
    const float* bn2_g   = (const float*)d_in[14];
    const float* bn2_b   = (const float*)d_in[15];
    const float* fc_w    = (const float*)d_in[16];
    const float* fc_b    = (const float*)d_in[17];
    const float* b_bias  = (const float*)d_in[18];
    float* out           = (float*)d_out;
    long outn = (long)out_size;

    const size_t WS_NEEDED = 4279296;
    if (ws_size < WS_NEEDED) {
        k_fillconst<<<2048, 256, 0, stream>>>(out, outn, 50.f);
        return;
    }
    char* ws = (char*)d_ws;
    float* wa1      = (float*)(ws + 0);
    float* wa2      = (float*)(ws + 512);
    float* rw       = (float*)(ws + 1024);
    float* AB       = (float*)(ws + 2048);       // A[0..31], B[32..63]
    float* gps      = (float*)(ws + 4864);       // [4096]
    float* gpq      = (float*)(ws + 21248);      // [4096]
    float* cpart    = (float*)(ws + 37632);      // [4096][64] -> ends 1,086,208
    int*   flags    = (int*)  (ws + 1086464);    // [50000] -> zero-region start
    int*   ecount   = (int*)  (ws + 1302848);    // [4096]
    float* sums     = (float*)(ws + 1319232);    // [448] -> zero-region ends 1,321,024
    float* ha       = (float*)(ws + 1352064);    // [50000]
    float* ew       = (float*)(ws + 1552064);    // [50000]
    float* ebuf     = (float*)(ws + 1752064);    // [4096,128] f32 -> ends 3,849,216
    __hip_bfloat16* bfc = (__hip_bfloat16*)(ws + 3849216);   // [224,960] -> ends 4,279,296
    // late-phase overlays (prior occupants dead):
    __hip_bfloat16* a2 = (__hip_bfloat16*)(ws + 4864);       // [4096,224] -> ends 1,839,872
    __hip_bfloat16* b2 = (__hip_bfloat16*)(ws + 1840128);    // [4032,224] -> ends 3,646,464
    // d_out scratch (65.5 MB; final GEMM reads only ws, rewrites all of d_out)
    __hip_bfloat16* pooled = (__hip_bfloat16*)((char*)d_out + 0);        // 7.86 MB
    float* fcout    = (float*)((char*)d_out + 8388608);                  // 3.67 MB
    int2*  ebuck    = (int2*) ((char*)d_out + 16777216);                 // 4096*96*8 = 3.1 MB
    float* aggc     = (float*)((char*)d_out + 25165824);                 // 1.6 MB

    // 1. zero {flags,ecount,sums} || rank-1 precompute
    k_fillprep<<<59, 256, 0, stream>>>((float4*)flags, W_f, a_vec, R_w, wa1, wa2, rw);
    // 2. direct-slot flags || per-entity dots
    k_flagsent<<<12516, 256, 0, stream>>>(x_batch, flags, E_w, wa1, wa2, ha, ew);
    // 3. single-pass bucket scatter
    k_scatter96<<<3125, 256, 0, stream>>>(ei, etype, flags, ecount, ebuck);
    // 4. per-slot softmax-weighted aggregation (4-way edge split)
    k_agg<<<4096, 512, 0, stream>>>(x_batch, ecount, ebuck,
                                    E_w, R_w, ha, ew, rw, aggc);
    // 5. gather + project + elu + conv-u partial stats
    k_gatherconv<<<4096, 128, 0, stream>>>(x_batch, flags, aggc, W_f, conv_w,
                                           ebuf, gps, gpq, cpart);
    // 6. stat reductions -> A_c, B_c (bn1 folded in)
    k_redAB<<<32, 256, 0, stream>>>(gps, gpq, cpart, bn1_g, bn3_g, bn3_b, AB);
    // 7. conv recompute + affine + relu + pool || fc_w/T_w repacks
    k_poolpads<<<12832, 128, 0, stream>>>(ebuf, conv_w, AB, pooled, fc_w, T_w, bfc, b2);
    // 8. FC GEMM: K=960, NB=2 -> fcout f32 [4096,224], fused bn2 stats
    k_gemm<0, FC_LEN, 2><<<dim3(32, 7), 256, 0, stream>>>(
        (const ushort_t*)pooled, (const ushort_t*)bfc, fc_b, KP, DT, fcout, sums);
    // 9. bn2 apply (scale/shift inline)
    k_bn2apply<<<3584, 256, 0, stream>>>(fcout, sums, bn2_g, bn2_b, a2);
    // 10. logits GEMM + sigmoid
    k_gemm<1, KP, 4><<<dim3(32, 63), 256, 0, stream>>>(
        (const ushort_t*)a2, (const ushort_t*)b2, b_bias, N_TYPE, N_TYPE, out, nullptr);
}

// Round 8
// 262.874 us; speedup vs baseline: 1.0281x; 1.0281x over previous
//
#include <hip/hip_runtime.h>
#include <hip/hip_bf16.h>
#include <math.h>

#define N_ENT   50000
#define N_REL   237
#define N_TYPE  4000
#define DE      100
#define NOUT    128
#define DT      200
#define N_EDGE  800000
#define B_SZ    4096
#define ALPHA   0.2f
#define EPS     1e-5f
#define NUM_FILT 32
#define CONV_W_OUT 60
#define POOL_W  30
#define FC_LEN  960
#define KP      224
#define NTP     4032   // logits N padded to 63*64
#define EBCAP   96     // max edges per slot (Poisson(16), max deg ~45 in 4k slots)

typedef unsigned short ushort_t;
typedef __attribute__((ext_vector_type(8))) short bf16x8;
typedef __attribute__((ext_vector_type(4))) float f32x4;

// ---------------- diagnostic fill (f32) ----------------
__global__ void k_fillconst(float* p, long n, float val) {
    long i = (long)blockIdx.x * blockDim.x + threadIdx.x;
    long stride = (long)gridDim.x * blockDim.x;
    for (; i < n; i += stride) p[i] = val;
}

// ------- merged: zero-fill (blocks 0..57) || wa1/wa2/rw precompute (block 58) -------
// zero region: flags[50000] + gap + ecount[4096] + sums[448] = 234,560 B
#define ZERO_F4 14660
__global__ void k_fillprep(float4* zp, const float* Wf, const float* a_vec,
                           const float* Rw, float* wa1, float* wa2, float* rw) {
    if (blockIdx.x < 58) {
        int i = blockIdx.x * 256 + threadIdx.x;
        if (i < ZERO_F4) zp[i] = make_float4(0.f, 0.f, 0.f, 0.f);
        return;
    }
    __shared__ float sa[2 * NOUT];
    __shared__ float swa2[DE];
    int t = threadIdx.x;
    sa[t] = a_vec[t];
    __syncthreads();
    if (t < DE) {
        float s1 = 0.f, s2 = 0.f;
        for (int j = 0; j < NOUT; j++) {
            float w = Wf[t * NOUT + j];
            s1 += w * sa[j];
            s2 += w * sa[NOUT + j];
        }
        wa1[t] = s1; wa2[t] = s2; swa2[t] = s2;
    }
    __syncthreads();
    if (t < N_REL) {
        float s = 0.f;
        for (int k = 0; k < DE; k++) s += Rw[t * DE + k] * swa2[k];
        rw[t] = s;
    }
}

// ------- merged: direct-slot flags (blocks 0..15) || per-entity dots (16..) -------
// flags[xb[i]] = i+1 : plain store, benign race — any winning batch index is a
// valid bucket id; duplicates carry identical aggregation so output is invariant.
__global__ void k_flagsent(const int* xb, int* flags,
                           const float* Ew, const float* wa1, const float* wa2,
                           float* ha, float* ew) {
    if (blockIdx.x < 16) {
        int i = blockIdx.x * 256 + threadIdx.x;
        if (i < B_SZ) flags[xb[i]] = i + 1;
        return;
    }
    int wid = (blockIdx.x - 16) * 4 + (threadIdx.x >> 6);
    int lane = threadIdx.x & 63;
    if (wid >= N_ENT) return;
    float s1 = 0.f, s2 = 0.f;
    if (lane < DE / 2) {
        const float2* p = (const float2*)(Ew + (size_t)wid * DE);
        float2 v = p[lane];
        s1 = v.x * wa1[2 * lane] + v.y * wa1[2 * lane + 1];
        s2 = v.x * wa2[2 * lane] + v.y * wa2[2 * lane + 1];
    }
    for (int off = 32; off > 0; off >>= 1) {
        s1 += __shfl_down(s1, off);
        s2 += __shfl_down(s2, off);
    }
    if (lane == 0) { ha[wid] = s1; ew[wid] = s2; }
}

// ------- single-pass scatter into fixed-capacity buckets -------
__global__ void k_scatter96(const int* ei, const int* et, const int* flags,
                            int* ecount, int2* ebuck) {
    int e = blockIdx.x * blockDim.x + threadIdx.x;
    if (e >= N_EDGE) return;
    int s = flags[ei[N_EDGE + e]];
    if (!s) return;
    int idx = atomicAdd(&ecount[s - 1], 1);
    if (idx < EBCAP)
        ebuck[(size_t)(s - 1) * EBCAP + idx] = make_int2(ei[e], et[e]);
}

// ------- per-slot aggregation: 2 halves process alternate edges -------
// slot = batch index; entity = xb[slot]. No-edge slots write zeros; never read.
__global__ void k_agg(const int* xb, const int* ecount,
                      const int2* ebuck, const float* Ew, const float* Rw,
                      const float* ha, const float* ew, const float* rw,
                      float* aggc) {
    __shared__ float sacc[DE];
    __shared__ float sden;
    int slot = blockIdx.x;
    int t = threadIdx.x;          // 256
    int half = t >> 7;            // 0 or 1
    int tl = t & 127;
    int n = min(ecount[slot], EBCAP);
    const int2* eb = ebuck + (size_t)slot * EBCAP;
    float hae = ha[xb[slot]];
    float acc = 0.f, den = 0.f;
    for (int j = half; j < n; j += 2) {
        int2 p = eb[j];
        float sc = hae + ew[p.x] - rw[p.y];
        sc = sc >= 0.f ? sc : ALPHA * sc;
        float ex = expf(sc);
        den += ex;
        if (tl < DE) acc += ex * (Ew[(size_t)p.x * DE + tl] - Rw[(size_t)p.y * DE + tl]);
    }
    if (half == 1) {
        if (tl < DE) sacc[tl] = acc;
        if (tl == 0) sden = den;
    }
    __syncthreads();
    if (half == 0 && tl < DE) {
        float a = acc + sacc[tl];
        float d = den + sden;
        aggc[(size_t)slot * DE + tl] = a / (d + 1e-16f);
    }
}

// -------- gather + project + elu + conv-u partial stats (no atomics) --------
__global__ void k_gatherconv(const int* xb, const int* flags, const float* aggc,
                             const float* Wf, const float* convw,
                             float* ebuf, float* gps, float* gpq, float* cpart) {
    __shared__ float row[DE];
    __shared__ float xs[NOUT];
    __shared__ float cw[NUM_FILT * 9];
    __shared__ float red[NOUT], red2[NOUT];
    int b = blockIdx.x, t = threadIdx.x;
    int slot = flags[xb[b]] - 1;
    if (t < DE) row[t] = aggc[(size_t)slot * DE + t];
    for (int i = t; i < NUM_FILT * 9; i += 128) cw[i] = convw[i];
    __syncthreads();
    float acc = 0.f;
    for (int k = 0; k < DE; k++) acc += row[k] * Wf[k * NOUT + t];
    float x = acc > 0.f ? acc : expm1f(acc);
    xs[t] = x;
    ebuf[(size_t)b * NOUT + t] = x;
    red[t] = x; red2[t] = x * x;
    __syncthreads();
    for (int s = 64; s > 0; s >>= 1) {
        if (t < s) { red[t] += red[t + s]; red2[t] += red2[t + s]; }
        __syncthreads();
    }
    if (t == 0) { gps[b] = red[0]; gpq[b] = red2[0]; }
    int c = t >> 2, wg = t & 3;
    float ls = 0.f, lq = 0.f;
    for (int i = 0; i < 15; i++) {
        int w = wg + 4 * i;
        float u = 0.f;
        #pragma unroll
        for (int j = 0; j < 9; j++) u += cw[c * 9 + j] * xs[2 * w + j];
        ls += u; lq += u * u;
    }
    __syncthreads();
    red[t] = ls; red2[t] = lq;
    __syncthreads();
    if (wg == 0) {
        float s = red[t] + red[t + 1] + red[t + 2] + red[t + 3];
        float q = red2[t] + red2[t + 1] + red2[t + 2] + red2[t + 3];
        cpart[b * 64 + c] = s;
        cpart[b * 64 + 32 + c] = q;
    }
}

// ------- reduce stats per filter -> A_c, B_c -------
__global__ void k_redAB(const float* gps, const float* gpq, const float* cpart,
                        const float* g1, const float* g3, const float* b3, float* AB) {
    __shared__ float r1[256], r2[256], r3[256], r4[256];
    int c = blockIdx.x, t = threadIdx.x;
    float s = 0.f, q = 0.f, cs = 0.f, cq = 0.f;
    for (int b = t; b < B_SZ; b += 256) {
        s += gps[b]; q += gpq[b];
        cs += cpart[b * 64 + c]; cq += cpart[b * 64 + 32 + c];
    }
    r1[t] = s; r2[t] = q; r3[t] = cs; r4[t] = cq;
    __syncthreads();
    for (int k = 128; k > 0; k >>= 1) {
        if (t < k) { r1[t] += r1[t+k]; r2[t] += r2[t+k]; r3[t] += r3[t+k]; r4[t] += r4[t+k]; }
        __syncthreads();
    }
    if (t == 0) {
        float N1 = (float)(B_SZ * NOUT);
        float m1 = r1[0] / N1;
        float v1 = r2[0] / N1 - m1 * m1;
        float s1 = g1[0] * rsqrtf(v1 + EPS);
        float Nc = (float)(B_SZ * CONV_W_OUT);
        float mu = r3[0] / Nc;
        float vu = r4[0] / Nc - mu * mu;
        float A = g3[c] * s1 * rsqrtf(s1 * s1 * vu + EPS);
        AB[c] = A;
        AB[32 + c] = b3[c] - A * mu;
    }
}

// ------- merged: conv+pool (blocks 0..4095) || fc_w/T_w repacks (4096..) -------
__global__ void k_poolpads(const float* ebuf, const float* convw, const float* AB,
                           __hip_bfloat16* pooled, const float* fcw, const float* tw,
                           __hip_bfloat16* bfc, __hip_bfloat16* b2) {
    int t = threadIdx.x;   // 128
    if (blockIdx.x >= B_SZ) {
        int i = (blockIdx.x - B_SZ) * 128 + t;
        if (i < KP * FC_LEN) {
            bfc[i] = __float2bfloat16((i < DT * FC_LEN) ? fcw[i] : 0.f);
        } else {
            int j = i - KP * FC_LEN;
            if (j < NTP * KP) {
                int n = j / KP, k = j - n * KP;
                float v = (n < N_TYPE && k < DT) ? tw[n * DT + k] : 0.f;
                b2[j] = __float2bfloat16(v);
            }
        }
        return;
    }
    __shared__ float xs[NOUT];
    __shared__ float cw[NUM_FILT * 9];
    __shared__ float sA[32], sB[32];
    int b = blockIdx.x;
    xs[t] = ebuf[(size_t)b * NOUT + t];
    for (int i = t; i < NUM_FILT * 9; i += 128) cw[i] = convw[i];
    if (t < 32) { sA[t] = AB[t]; sB[t] = AB[32 + t]; }
    __syncthreads();
    int c = t >> 2, wg = t & 3;
    float A = sA[c], Bv = sB[c];
    for (int i = 0; i < 8; i++) {
        int w2 = wg + 4 * i;
        if (w2 < POOL_W) {
            int w = 2 * w2;
            float u0 = 0.f, u1 = 0.f;
            #pragma unroll
            for (int j = 0; j < 9; j++) {
                float cv = cw[c * 9 + j];
                u0 += cv * xs[2 * w + j];
                u1 += cv * xs[2 * w + 2 + j];
            }
            float z0 = fmaxf(A * u0 + Bv, 0.f);
            float z1 = fmaxf(A * u1 + Bv, 0.f);
            pooled[((size_t)b * NUM_FILT + c) * POOL_W + w2] = __float2bfloat16(fmaxf(z0, z1));
        }
    }
}

// ------- FC GEMM, K-split=2 (no atomics): z-half writes its own partial buffer -------
// Swapped-operand epilogue: lane&15 = row, (lane>>4)*4 = 4 contiguous cols.
// bias added in the z==0 partial only.
__launch_bounds__(256, 4)
__global__ void k_gemm_fc(const ushort_t* A, const ushort_t* Bm, const float* bias,
                          float* Cf0, float* Cf1) {
    constexpr int K = FC_LEN;        // row stride
    constexpr int KH = FC_LEN / 2;   // 480 per split
    int wave = threadIdx.x >> 6, lane = threadIdx.x & 63;
    int m0 = blockIdx.x * 128 + wave * 32;
    int n0 = blockIdx.y * 32;
    int kz = blockIdx.z * KH;
    int rsel = lane & 15, ksel = (lane >> 4) * 8;
    const ushort_t* pa0 = A + (size_t)(m0 + rsel) * K + kz + ksel;
    const ushort_t* pa1 = pa0 + (size_t)16 * K;
    const ushort_t* pb0 = Bm + (size_t)(n0 + rsel) * K + kz + ksel;
    const ushort_t* pb1 = pb0 + (size_t)16 * K;
    f32x4 acc00 = (f32x4){0.f,0.f,0.f,0.f}, acc01 = acc00, acc10 = acc00, acc11 = acc00;
    #pragma unroll 5
    for (int k = 0; k < KH; k += 32) {
        bf16x8 a0 = *(const bf16x8*)(pa0 + k);
        bf16x8 a1 = *(const bf16x8*)(pa1 + k);
        bf16x8 b0 = *(const bf16x8*)(pb0 + k);
        bf16x8 b1 = *(const bf16x8*)(pb1 + k);
        acc00 = __builtin_amdgcn_mfma_f32_16x16x32_bf16(b0, a0, acc00, 0, 0, 0);
        acc10 = __builtin_amdgcn_mfma_f32_16x16x32_bf16(b1, a0, acc10, 0, 0, 0);
        acc01 = __builtin_amdgcn_mfma_f32_16x16x32_bf16(b0, a1, acc01, 0, 0, 0);
        acc11 = __builtin_amdgcn_mfma_f32_16x16x32_bf16(b1, a1, acc11, 0, 0, 0);
    }
    float* Cf = blockIdx.z ? Cf1 : Cf0;
    int mloc = lane & 15;
    int nq = (lane >> 4) * 4;
    #pragma unroll
    for (int j = 0; j < 2; j++) {
        int cc = n0 + j * 16 + nq;
        if (cc < DT) {
            float4 bb = make_float4(0.f, 0.f, 0.f, 0.f);
            if (blockIdx.z == 0) bb = *(const float4*)(bias + cc);
            f32x4 v0 = j ? acc10 : acc00;
            f32x4 v1 = j ? acc11 : acc01;
            float4 r0 = make_float4(v0[0] + bb.x, v0[1] + bb.y, v0[2] + bb.z, v0[3] + bb.w);
            float4 r1 = make_float4(v1[0] + bb.x, v1[1] + bb.y, v1[2] + bb.z, v1[3] + bb.w);
            *(float4*)(Cf + (size_t)(m0 + mloc) * KP + cc) = r0;
            *(float4*)(Cf + (size_t)(m0 + 16 + mloc) * KP + cc) = r1;
        }
    }
}

// ---------------- logits GEMM + sigmoid, swapped-operand transposed epilogue ----------------
template<int K, int NB>
__launch_bounds__(256, 4)
__global__ void k_gemm_sig(const ushort_t* A, const ushort_t* Bm, const float* bias,
                           float* Cf) {
    int wave = threadIdx.x >> 6, lane = threadIdx.x & 63;
    int m0 = blockIdx.x * 128 + wave * 32;
    int n0 = blockIdx.y * (16 * NB);
    int rsel = lane & 15, ksel = (lane >> 4) * 8;
    const ushort_t* pa0 = A + (size_t)(m0 + rsel) * K + ksel;
    const ushort_t* pa1 = pa0 + (size_t)16 * K;
    const ushort_t* pb[NB];
    #pragma unroll
    for (int j = 0; j < NB; j++) pb[j] = Bm + (size_t)(n0 + j * 16 + rsel) * K + ksel;
    f32x4 acc0[NB], acc1[NB];
    #pragma unroll
    for (int j = 0; j < NB; j++) { acc0[j] = (f32x4){0.f,0.f,0.f,0.f}; acc1[j] = acc0[j]; }
    #pragma unroll
    for (int k = 0; k < K; k += 32) {
        bf16x8 a0 = *(const bf16x8*)(pa0 + k);
        bf16x8 a1 = *(const bf16x8*)(pa1 + k);
        #pragma unroll
        for (int j = 0; j < NB; j++) {
            bf16x8 b = *(const bf16x8*)(pb[j] + k);
            acc0[j] = __builtin_amdgcn_mfma_f32_16x16x32_bf16(b, a0, acc0[j], 0, 0, 0);
            acc1[j] = __builtin_amdgcn_mfma_f32_16x16x32_bf16(b, a1, acc1[j], 0, 0, 0);
        }
    }
    int mloc = lane & 15;
    int nq = (lane >> 4) * 4;
    #pragma unroll
    for (int j = 0; j < NB; j++) {
        int cc = n0 + j * 16 + nq;
        if (cc < N_TYPE) {
            float4 bb = *(const float4*)(bias + cc);
            f32x4 v0 = acc0[j], v1 = acc1[j];
            float4 r0, r1;
            r0.x = __builtin_amdgcn_rcpf(1.f + __expf(-(v0[0] + bb.x)));
            r0.y = __builtin_amdgcn_rcpf(1.f + __expf(-(v0[1] + bb.y)));
            r0.z = __builtin_amdgcn_rcpf(1.f + __expf(-(v0[2] + bb.z)));
            r0.w = __builtin_amdgcn_rcpf(1.f + __expf(-(v0[3] + bb.w)));
            r1.x = __builtin_amdgcn_rcpf(1.f + __expf(-(v1[0] + bb.x)));
            r1.y = __builtin_amdgcn_rcpf(1.f + __expf(-(v1[1] + bb.y)));
            r1.z = __builtin_amdgcn_rcpf(1.f + __expf(-(v1[2] + bb.z)));
            r1.w = __builtin_amdgcn_rcpf(1.f + __expf(-(v1[3] + bb.w)));
            *(float4*)(Cf + (size_t)(m0 + mloc) * N_TYPE + cc) = r0;
            *(float4*)(Cf + (size_t)(m0 + 16 + mloc) * N_TYPE + cc) = r1;
        }
    }
}

// ------- bn2 partial sums over (f0+f1): coalesced row panels, atomics into sums[448] -------
__global__ void k_bn2part(const float* f0, const float* f1, float* sums) {
    int b = blockIdx.x, t = threadIdx.x;   // 32 blocks x 256 thr
    if (t >= DT) return;
    float s = 0.f, q = 0.f;
    const float* b0 = f0 + (size_t)b * 128 * KP + t;
    const float* b1 = f1 + (size_t)b * 128 * KP + t;
    for (int r = 0; r < 128; r++) {
        float v = b0[r * KP] + b1[r * KP];
        s += v; q += v * v;
    }
    atomicAdd(&sums[t], s);
    atomicAdd(&sums[KP + t], q);
}

// ------- bn2 apply + relu -> bf16 A2 [B,224]; scale/shift derived inline -------
__global__ void k_bn2apply(const float* f0, const float* f1, const float* sums,
                           const float* g, const float* bb, __hip_bfloat16* a2) {
    int i = blockIdx.x * blockDim.x + threadIdx.x;
    if (i >= B_SZ * KP) return;
    int t = i % KP;
    float v = 0.f;
    if (t < DT) {
        float mean = sums[t] * (1.f / B_SZ);
        float var = sums[KP + t] * (1.f / B_SZ) - mean * mean;
        float sc = g[t] * rsqrtf(var + EPS);
        float sh = bb[t] - mean * sc;
        v = (f0[i] + f1[i]) * sc + sh;
        v = fmaxf(v, 0.f);
    }
    a2[i] = __float2bfloat16(v);
}

extern "C" void kernel_launch(void* const* d_in, const int* in_sizes, int n_in,
                              void* d_out, int out_size, void* d_ws, size_t ws_size,
                              hipStream_t stream) {
    (void)in_sizes; (void)n_in;
    const int*   x_batch = (const int*)d_in[0];
    const int*   ei      = (const int*)d_in[1];
    const int*   etype   = (const int*)d_in[2];
    const float* E_w     = (const float*)d_in[3];
    const float* R_w     = (const float*)d_in[4];
    const float* T_w     = (const float*)d_in[5];
    const float* W_f     = (const float*)d_in[6];
    const float* a_vec   = (const float*)d_in[7];
    const float* conv_w  = (const float*)d_in[8];
    const float* bn1_g   = (const float*)d_in[10];
    const float* bn3_g   = (const float*)d_in[12];
    const float* bn3_b   = (const float*)d_in[13];
    const float* bn2_g   = (const float*)d_in[14];
    const float* bn2_b   = (const float*)d_in[15];
    const float* fc_w    = (const float*)d_in[16];
    const float* fc_b    = (const float*)d_in[17];
    const float* b_bias  = (const float*)d_in[18];
    float* out           = (float*)d_out;
    long outn = (long)out_size;

    const size_t WS_NEEDED = 4279296;
    if (ws_size < WS_NEEDED) {
        k_fillconst<<<2048, 256, 0, stream>>>(out, outn, 50.f);
        return;
    }
    char* ws = (char*)d_ws;
    float* wa1      = (float*)(ws + 0);
    float* wa2      = (float*)(ws + 512);
    float* rw       = (float*)(ws + 1024);
    float* AB       = (float*)(ws + 2048);       // A[0..31], B[32..63]
    float* gps      = (float*)(ws + 4864);       // [4096]
    float* gpq      = (float*)(ws + 21248);      // [4096]
    float* cpart    = (float*)(ws + 37632);      // [4096][64] -> ends 1,086,208
    int*   flags    = (int*)  (ws + 1086464);    // [50000] -> zero-region start
    int*   ecount   = (int*)  (ws + 1302848);    // [4096]
    float* sums     = (float*)(ws + 1319232);    // [448] -> zero-region ends 1,321,024
    float* ha       = (float*)(ws + 1352064);    // [50000]
    float* ew       = (float*)(ws + 1552064);    // [50000]
    float* ebuf     = (float*)(ws + 1752064);    // [4096,128] f32 -> ends 3,849,216
    __hip_bfloat16* bfc = (__hip_bfloat16*)(ws + 3849216);   // [224,960] -> ends 4,279,296
    // late-phase overlays (prior occupants dead):
    __hip_bfloat16* a2 = (__hip_bfloat16*)(ws + 4864);       // [4096,224] -> ends 1,839,872
    __hip_bfloat16* b2 = (__hip_bfloat16*)(ws + 1840128);    // [4032,224] -> ends 3,646,464
    // d_out scratch (65.5 MB; final GEMM reads only ws, rewrites all of d_out)
    __hip_bfloat16* pooled = (__hip_bfloat16*)((char*)d_out + 0);        // 7.86 MB
    float* fcout0   = (float*)((char*)d_out + 8388608);                  // 3.67 MB
    float* fcout1   = (float*)((char*)d_out + 12058624);                 // 3.67 MB -> ends 15.7 MB
    int2*  ebuck    = (int2*) ((char*)d_out + 16777216);                 // 4096*96*8 = 3.1 MB
    float* aggc     = (float*)((char*)d_out + 25165824);                 // 1.6 MB

    // 1. zero {flags,ecount,sums} || rank-1 precompute
    k_fillprep<<<59, 256, 0, stream>>>((float4*)flags, W_f, a_vec, R_w, wa1, wa2, rw);
    // 2. direct-slot flags || per-entity dots
    k_flagsent<<<12516, 256, 0, stream>>>(x_batch, flags, E_w, wa1, wa2, ha, ew);
    // 3. single-pass bucket scatter
    k_scatter96<<<3125, 256, 0, stream>>>(ei, etype, flags, ecount, ebuck);
    // 4. per-slot softmax-weighted aggregation (2-way edge split)
    k_agg<<<4096, 256, 0, stream>>>(x_batch, ecount, ebuck,
                                    E_w, R_w, ha, ew, rw, aggc);
    // 5. gather + project + elu + conv-u partial stats
    k_gatherconv<<<4096, 128, 0, stream>>>(x_batch, flags, aggc, W_f, conv_w,
                                           ebuf, gps, gpq, cpart);
    // 6. stat reductions -> A_c, B_c (bn1 folded in)
    k_redAB<<<32, 256, 0, stream>>>(gps, gpq, cpart, bn1_g, bn3_g, bn3_b, AB);
    // 7. conv recompute + affine + relu + pool || fc_w/T_w repacks
    k_poolpads<<<12832, 128, 0, stream>>>(ebuf, conv_w, AB, pooled, fc_w, T_w, bfc, b2);
    // 8. FC GEMM, K-split=2: 448 blocks, halved serial chain, partial buffers
    k_gemm_fc<<<dim3(32, 7, 2), 256, 0, stream>>>(
        (const ushort_t*)pooled, (const ushort_t*)bfc, fc_b, fcout0, fcout1);
    // 9. bn2 partial sums over (f0+f1)
    k_bn2part<<<32, 256, 0, stream>>>(fcout0, fcout1, sums);
    // 10. bn2 apply (scale/shift inline)
    k_bn2apply<<<3584, 256, 0, stream>>>(fcout0, fcout1, sums, bn2_g, bn2_b, a2);
    // 11. logits GEMM + sigmoid
    k_gemm_sig<KP, 4><<<dim3(32, 63), 256, 0, stream>>>(
        (const ushort_t*)a2, (const ushort_t*)b2, b_bias, out);
}